// Round 2
// baseline (670.595 us; speedup 1.0000x reference)
//
#include <hip/hip_runtime.h>
#include <math.h>

// SplineConv x2 (K=4, dim=1, degree=1, mean aggr) + ELU + log_softmax.
// Strategy: build CSR by dst once (reused by both layers); per-layer
// dense xw = x @ [W_k | root] precompute; gather-based aggregation with
// one lane-group per node (no float atomics).
// NOTE: harness delivers integer inputs as int32 (edge_index is int*, not
// long long*) — reading int64 here caused the round-1 memory fault.

#define F_IN   48
#define HID    32
#define NCLS   10
#define KS     4
// xw1 row: [k*32+o | 128+o(root)] -> 160 cols. xw2 row: [k*10+o | 40+o] -> 50 cols.
#define XW1_COLS 160
#define XW2_COLS 50

__global__ void zero_int_kernel(int* __restrict__ p, int n) {
    int i = blockIdx.x * blockDim.x + threadIdx.x;
    if (i < n) p[i] = 0;
}

__global__ void hist_kernel(const int* __restrict__ ei, int* __restrict__ cnt, int E) {
    int e = blockIdx.x * blockDim.x + threadIdx.x;
    if (e < E) atomicAdd(&cnt[ei[E + e]], 1);
}

// Single-block exclusive scan over N counts -> offs[0..N], also copy to cur.
__global__ void scan_kernel(const int* __restrict__ cnt, int* __restrict__ offs,
                            int* __restrict__ cur, int n) {
    __shared__ int part[1024];
    int t = threadIdx.x;
    int chunk = (n + 1023) / 1024;
    int beg = t * chunk;
    int end = min(beg + chunk, n);
    int s = 0;
    for (int i = beg; i < end; ++i) s += cnt[i];
    part[t] = s;
    __syncthreads();
    for (int off = 1; off < 1024; off <<= 1) {
        int v = (t >= off) ? part[t - off] : 0;
        __syncthreads();
        part[t] += v;
        __syncthreads();
    }
    int run = part[t] - s;  // exclusive prefix of this chunk
    for (int i = beg; i < end; ++i) {
        offs[i] = run;
        cur[i] = run;
        run += cnt[i];
    }
    if (t == 1023) offs[n] = part[1023];
}

// Scatter edges into dst-sorted order; payload = packed(src|k0<<20) + frac.
__global__ void scatter_kernel(const int* __restrict__ ei, const float* __restrict__ ea,
                               int* __restrict__ cur, int* __restrict__ spk,
                               float* __restrict__ sfr, int E) {
    int e = blockIdx.x * blockDim.x + threadIdx.x;
    if (e >= E) return;
    int src = ei[e];
    int dst = ei[E + e];
    float u = ea[e];
    float v = u * (float)(KS - 1);
    float vf = floorf(v);
    int k0 = min(max((int)vf, 0), KS - 1);
    float fr = v - vf;
    int pos = atomicAdd(&cur[dst], 1);
    spk[pos] = src | (k0 << 20);
    sfr[pos] = fr;
}

// out[n, col] = x[n,:] . Wcol ; cols [0, K*fout) from W, [K*fout, K*fout+fout) from root.
__global__ void xw_kernel(const float* __restrict__ X, const float* __restrict__ W,
                          const float* __restrict__ R, float* __restrict__ out,
                          int n, int fin, int fout, int ncol) {
    int total = n * ncol;
    int kf = ncol - fout;  // K*fout
    for (int id = blockIdx.x * blockDim.x + threadIdx.x; id < total;
         id += gridDim.x * blockDim.x) {
        int node = id / ncol;
        int col = id - node * ncol;
        const float* wcol;
        if (col < kf) {
            int k = col / fout;
            int o = col - k * fout;
            wcol = W + (size_t)k * fin * fout + o;
        } else {
            wcol = R + (col - kf);
        }
        const float* xr = X + (size_t)node * fin;
        float acc = 0.f;
#pragma unroll 8
        for (int f = 0; f < fin; ++f) acc = fmaf(xr[f], wcol[(size_t)f * fout], acc);
        out[id] = acc;
    }
}

// Layer-1 aggregation: 32 lanes per node (c = channel). mean + root + bias + ELU.
__global__ void agg1_kernel(const float* __restrict__ xw1, const int* __restrict__ offs,
                            const int* __restrict__ spk, const float* __restrict__ sfr,
                            const float* __restrict__ bias, float* __restrict__ h, int n) {
    int c = threadIdx.x & 31;
    int node = blockIdx.x * 8 + (threadIdx.x >> 5);
    if (node >= n) return;
    int beg = offs[node];
    int end = offs[node + 1];
    float sum = 0.f;
    for (int e = beg; e < end; ++e) {
        int p = spk[e];
        float fr = sfr[e];
        int src = p & 0xFFFFF;
        int k0 = p >> 20;
        int k1 = min(k0 + 1, KS - 1);
        const float* row = xw1 + (size_t)src * XW1_COLS;
        float v0 = row[k0 * HID + c];
        float v1 = row[k1 * HID + c];
        sum += fmaf(fr, v1 - v0, v0);
    }
    int deg = end - beg;
    float m = sum / (float)(deg > 0 ? deg : 1);
    float o = m + xw1[(size_t)node * XW1_COLS + KS * HID + c] + bias[c];
    h[(size_t)node * HID + c] = (o > 0.f) ? o : expm1f(o);
}

// Layer-2 aggregation + log_softmax: 16 lanes per node, channels 0..9 active.
__global__ void agg2_kernel(const float* __restrict__ xw2, const int* __restrict__ offs,
                            const int* __restrict__ spk, const float* __restrict__ sfr,
                            const float* __restrict__ bias, float* __restrict__ out, int n) {
    int c = threadIdx.x & 15;
    int node = blockIdx.x * 16 + (threadIdx.x >> 4);
    if (node >= n) return;
    int cc = min(c, NCLS - 1);  // clamp so inactive lanes read in-bounds
    int beg = offs[node];
    int end = offs[node + 1];
    float sum = 0.f;
    for (int e = beg; e < end; ++e) {
        int p = spk[e];
        float fr = sfr[e];
        int src = p & 0xFFFFF;
        int k0 = p >> 20;
        int k1 = min(k0 + 1, KS - 1);
        const float* row = xw2 + (size_t)src * XW2_COLS;
        float v0 = row[k0 * NCLS + cc];
        float v1 = row[k1 * NCLS + cc];
        sum += fmaf(fr, v1 - v0, v0);
    }
    int deg = end - beg;
    float m = sum / (float)(deg > 0 ? deg : 1);
    float logit = m + xw2[(size_t)node * XW2_COLS + KS * NCLS + cc] + bias[cc];
    bool active = (c < NCLS);
    float mx = active ? logit : -INFINITY;
#pragma unroll
    for (int msk = 1; msk < 16; msk <<= 1) mx = fmaxf(mx, __shfl_xor(mx, msk, 16));
    float ex = active ? expf(logit - mx) : 0.f;
    float s = ex;
#pragma unroll
    for (int msk = 1; msk < 16; msk <<= 1) s += __shfl_xor(s, msk, 16);
    if (active) out[(size_t)node * NCLS + c] = (logit - mx) - logf(s);
}

extern "C" void kernel_launch(void* const* d_in, const int* in_sizes, int n_in,
                              void* d_out, int out_size, void* d_ws, size_t ws_size,
                              hipStream_t stream) {
    const float* x       = (const float*)d_in[0];
    const int*   ei      = (const int*)d_in[1];   // int32 per harness contract
    const float* ea      = (const float*)d_in[2];
    const float* W1      = (const float*)d_in[3];
    const float* root1   = (const float*)d_in[4];
    const float* bias1   = (const float*)d_in[5];
    const float* W2      = (const float*)d_in[6];
    const float* root2   = (const float*)d_in[7];
    const float* bias2   = (const float*)d_in[8];
    float* out = (float*)d_out;

    const int N = in_sizes[0] / F_IN;   // 50000
    const int E = in_sizes[2];          // 1600000

    // Workspace layout (~52 MB): xw2 aliases xw1 (disjoint lifetimes).
    size_t need = ((size_t)N * XW1_COLS + (size_t)N * HID) * 4   // xw1(+xw2 alias), h
                + ((size_t)3 * N + 1) * 4                        // cnt, offs, cur
                + (size_t)E * 8;                                 // spk, sfr
    if (ws_size < need) return;  // diagnostic: absmax-fail (poison) => ws too small

    float* xw1 = (float*)d_ws;                        // N * 160
    float* xw2 = xw1;                                 // alias: xw1 dead after agg1
    float* h   = xw1 + (size_t)N * XW1_COLS;          // N * 32
    int* cnt   = (int*)(h + (size_t)N * HID);         // N
    int* offs  = cnt + N;                             // N + 1
    int* cur   = offs + N + 1;                        // N
    int* spk   = cur + N;                             // E
    float* sfr = (float*)(spk + E);                   // E

    // 1) CSR build (shared by both layers)
    zero_int_kernel<<<(N + 255) / 256, 256, 0, stream>>>(cnt, N);
    hist_kernel<<<(E + 255) / 256, 256, 0, stream>>>(ei, cnt, E);
    scan_kernel<<<1, 1024, 0, stream>>>(cnt, offs, cur, N);
    scatter_kernel<<<(E + 255) / 256, 256, 0, stream>>>(ei, ea, cur, spk, sfr, E);

    // 2) Layer 1: xw1 = x @ [W1 | root1], aggregate + ELU -> h
    {
        int total = N * XW1_COLS;
        xw_kernel<<<(total + 255) / 256, 256, 0, stream>>>(x, W1, root1, xw1, N, F_IN, HID, XW1_COLS);
    }
    agg1_kernel<<<(N + 7) / 8, 256, 0, stream>>>(xw1, offs, spk, sfr, bias1, h, N);

    // 3) Layer 2: xw2 = h @ [W2 | root2], aggregate + log_softmax -> out
    {
        int total = N * XW2_COLS;
        xw_kernel<<<(total + 255) / 256, 256, 0, stream>>>(h, W2, root2, xw2, N, HID, NCLS, XW2_COLS);
    }
    agg2_kernel<<<(N + 15) / 16, 256, 0, stream>>>(xw2, offs, spk, sfr, bias2, out, N);
}

// Round 3
// 618.918 us; speedup vs baseline: 1.0835x; 1.0835x over previous
//
#include <hip/hip_runtime.h>
#include <math.h>

// SplineConv x2 (K=4, dim=1, degree=1, mean aggr) + ELU + log_softmax.
// CSR build by dst (counting sort) reused by both layers.
// Edge payload packed to ONE uint32: src(16b) | k0(2b) | qfrac(14b) —
// halves random-scatter lines (R2 showed 11x write amplification from
// cross-XCD partial-line writes: WRITE_SIZE 145MB for 12.8MB payload).
// Gather tables stored bf16 in [node][k][c] layout: per-edge gather is two
// contiguous 64B chunks (32 lanes x 2B) -> 205MB instead of 410MB traffic.
// Root/self path kept fp32 (separate per-node table) to bound bf16 noise.

#define F_IN   48
#define HID    32
#define NCLS   10
#define KS     4

__device__ inline unsigned short f2bf(float f) {
    unsigned x = __float_as_uint(f);
    unsigned r = x + 0x7FFFu + ((x >> 16) & 1u);  // RNE
    return (unsigned short)(r >> 16);
}
__device__ inline float bf2f(unsigned short u) {
    return __uint_as_float(((unsigned)u) << 16);
}

__global__ void hist_kernel(const int* __restrict__ ei, int* __restrict__ cnt, int E) {
    int e = blockIdx.x * blockDim.x + threadIdx.x;
    if (e < E) atomicAdd(&cnt[ei[E + e]], 1);
}

// Single-block exclusive scan over N counts -> offs[0..N], also copy to cur.
__global__ void scan_kernel(const int* __restrict__ cnt, int* __restrict__ offs,
                            int* __restrict__ cur, int n) {
    __shared__ int part[1024];
    int t = threadIdx.x;
    int chunk = (n + 1023) / 1024;
    int beg = t * chunk;
    int end = min(beg + chunk, n);
    int s = 0;
    for (int i = beg; i < end; ++i) s += cnt[i];
    part[t] = s;
    __syncthreads();
    for (int off = 1; off < 1024; off <<= 1) {
        int v = (t >= off) ? part[t - off] : 0;
        __syncthreads();
        part[t] += v;
        __syncthreads();
    }
    int run = part[t] - s;  // exclusive prefix of this chunk
    for (int i = beg; i < end; ++i) {
        offs[i] = run;
        cur[i] = run;
        run += cnt[i];
    }
    if (t == 1023) offs[n] = part[1023];
}

// Scatter edges into dst-sorted order; payload = src | k0<<16 | qfrac<<18.
__global__ void scatter_kernel(const int* __restrict__ ei, const float* __restrict__ ea,
                               int* __restrict__ cur, unsigned* __restrict__ spk, int E) {
    int e = blockIdx.x * blockDim.x + threadIdx.x;
    if (e >= E) return;
    int src = ei[e];
    int dst = ei[E + e];
    float u = ea[e];
    float v = u * (float)(KS - 1);
    float vf = floorf(v);
    int k0 = min(max((int)vf, 0), KS - 1);
    float fr = v - vf;                                // [0,1)
    unsigned qf = (unsigned)(fr * 16383.f + 0.5f);    // 14-bit
    unsigned pk = (unsigned)src | ((unsigned)k0 << 16) | (qf << 18);
    int pos = atomicAdd(&cur[dst], 1);
    spk[pos] = pk;
}

// outk[node][k][c] (bf16, kf = K*fout cols) ; outr[node][c] (fp32 root part).
__global__ void xw_kernel(const float* __restrict__ X, const float* __restrict__ W,
                          const float* __restrict__ R, unsigned short* __restrict__ outk,
                          float* __restrict__ outr, int n, int fin, int fout) {
    int kf = KS * fout;
    int ncol = kf + fout;
    int total = n * ncol;
    for (int id = blockIdx.x * blockDim.x + threadIdx.x; id < total;
         id += gridDim.x * blockDim.x) {
        int node = id / ncol;
        int col = id - node * ncol;
        const float* wcol;
        if (col < kf) {
            int k = col / fout;
            int o = col - k * fout;
            wcol = W + (size_t)k * fin * fout + o;
        } else {
            wcol = R + (col - kf);
        }
        const float* xr = X + (size_t)node * fin;
        float acc = 0.f;
#pragma unroll 8
        for (int f = 0; f < fin; ++f) acc = fmaf(xr[f], wcol[(size_t)f * fout], acc);
        if (col < kf) outk[(size_t)node * kf + col] = f2bf(acc);
        else outr[(size_t)node * fout + (col - kf)] = acc;
    }
}

__device__ inline float interp32(const unsigned short* __restrict__ xwk, unsigned p, int c) {
    int src = p & 0xFFFF;
    int k0 = (p >> 16) & 3;
    int k1 = min(k0 + 1, KS - 1);
    float fr = (float)(p >> 18) * (1.f / 16383.f);
    const unsigned short* row = xwk + (size_t)src * (KS * HID);
    float v0 = bf2f(row[k0 * HID + c]);
    float v1 = bf2f(row[k1 * HID + c]);
    return fmaf(fr, v1 - v0, v0);
}

// Layer-1 aggregation: 32 lanes per node (c = channel). mean + root + bias + ELU.
__global__ void agg1_kernel(const unsigned short* __restrict__ xwk,
                            const float* __restrict__ xroot,
                            const int* __restrict__ offs, const unsigned* __restrict__ spk,
                            const float* __restrict__ bias, float* __restrict__ h, int n) {
    int c = threadIdx.x & 31;
    int node = blockIdx.x * 8 + (threadIdx.x >> 5);
    if (node >= n) return;
    int beg = offs[node];
    int end = offs[node + 1];
    float s0 = 0.f, s1 = 0.f;
    int e = beg;
    for (; e + 2 <= end; e += 2) {
        unsigned p0 = spk[e];
        unsigned p1 = spk[e + 1];
        s0 += interp32(xwk, p0, c);
        s1 += interp32(xwk, p1, c);
    }
    if (e < end) s0 += interp32(xwk, spk[e], c);
    float sum = s0 + s1;
    int deg = end - beg;
    float m = sum / (float)(deg > 0 ? deg : 1);
    float o = m + xroot[(size_t)node * HID + c] + bias[c];
    h[(size_t)node * HID + c] = (o > 0.f) ? o : expm1f(o);
}

__device__ inline float interp10(const unsigned short* __restrict__ xwk, unsigned p, int cc) {
    int src = p & 0xFFFF;
    int k0 = (p >> 16) & 3;
    int k1 = min(k0 + 1, KS - 1);
    float fr = (float)(p >> 18) * (1.f / 16383.f);
    const unsigned short* row = xwk + (size_t)src * (KS * NCLS);
    float v0 = bf2f(row[k0 * NCLS + cc]);
    float v1 = bf2f(row[k1 * NCLS + cc]);
    return fmaf(fr, v1 - v0, v0);
}

// Layer-2 aggregation + log_softmax: 16 lanes per node, channels 0..9 active.
__global__ void agg2_kernel(const unsigned short* __restrict__ xwk,
                            const float* __restrict__ xroot,
                            const int* __restrict__ offs, const unsigned* __restrict__ spk,
                            const float* __restrict__ bias, float* __restrict__ out, int n) {
    int c = threadIdx.x & 15;
    int node = blockIdx.x * 16 + (threadIdx.x >> 4);
    if (node >= n) return;
    int cc = min(c, NCLS - 1);  // clamp so inactive lanes read in-bounds
    int beg = offs[node];
    int end = offs[node + 1];
    float s0 = 0.f, s1 = 0.f;
    int e = beg;
    for (; e + 2 <= end; e += 2) {
        unsigned p0 = spk[e];
        unsigned p1 = spk[e + 1];
        s0 += interp10(xwk, p0, cc);
        s1 += interp10(xwk, p1, cc);
    }
    if (e < end) s0 += interp10(xwk, spk[e], cc);
    float sum = s0 + s1;
    int deg = end - beg;
    float m = sum / (float)(deg > 0 ? deg : 1);
    float logit = m + xroot[(size_t)node * NCLS + cc] + bias[cc];
    bool active = (c < NCLS);
    float mx = active ? logit : -INFINITY;
#pragma unroll
    for (int msk = 1; msk < 16; msk <<= 1) mx = fmaxf(mx, __shfl_xor(mx, msk, 16));
    float ex = active ? expf(logit - mx) : 0.f;
    float s = ex;
#pragma unroll
    for (int msk = 1; msk < 16; msk <<= 1) s += __shfl_xor(s, msk, 16);
    if (active) out[(size_t)node * NCLS + c] = (logit - mx) - logf(s);
}

extern "C" void kernel_launch(void* const* d_in, const int* in_sizes, int n_in,
                              void* d_out, int out_size, void* d_ws, size_t ws_size,
                              hipStream_t stream) {
    const float* x       = (const float*)d_in[0];
    const int*   ei      = (const int*)d_in[1];   // int32 per harness contract
    const float* ea      = (const float*)d_in[2];
    const float* W1      = (const float*)d_in[3];
    const float* root1   = (const float*)d_in[4];
    const float* bias1   = (const float*)d_in[5];
    const float* W2      = (const float*)d_in[6];
    const float* root2   = (const float*)d_in[7];
    const float* bias2   = (const float*)d_in[8];
    float* out = (float*)d_out;

    const int N = in_sizes[0] / F_IN;   // 50000
    const int E = in_sizes[2];          // 1600000

    // Workspace layout (256B-aligned regions), ~33 MB total.
    char* base = (char*)d_ws;
    size_t off = 0;
    auto alloc = [&](size_t bytes) {
        char* p = base + off;
        off = (off + bytes + 255) & ~(size_t)255;
        return (void*)p;
    };
    unsigned short* xwk1 = (unsigned short*)alloc((size_t)N * KS * HID * 2);  // 12.8 MB
    float* xr1           = (float*)alloc((size_t)N * HID * 4);                // 6.4 MB
    float* h             = (float*)alloc((size_t)N * HID * 4);                // 6.4 MB
    int* cnt             = (int*)alloc((size_t)N * 4);
    int* offs            = (int*)alloc(((size_t)N + 1) * 4);
    int* cur             = (int*)alloc((size_t)N * 4);
    unsigned* spk        = (unsigned*)alloc((size_t)E * 4);                   // 6.4 MB
    // layer-2 tables alias layer-1 tables (xwk1/xr1 dead after agg1)
    unsigned short* xwk2 = xwk1;  // N*40 bf16 fits in N*128 region
    float* xr2           = xr1;   // N*10 fp32 fits in N*32 region
    if (ws_size < off) return;

    // 1) CSR build (shared by both layers)
    hipMemsetAsync(cnt, 0, (size_t)N * 4, stream);
    hist_kernel<<<(E + 255) / 256, 256, 0, stream>>>(ei, cnt, E);
    scan_kernel<<<1, 1024, 0, stream>>>(cnt, offs, cur, N);
    scatter_kernel<<<(E + 255) / 256, 256, 0, stream>>>(ei, ea, cur, spk, E);

    // 2) Layer 1: tables from x @ [W1 | root1]; aggregate + ELU -> h
    {
        int total = N * (KS * HID + HID);
        xw_kernel<<<(total + 255) / 256, 256, 0, stream>>>(x, W1, root1, xwk1, xr1, N, F_IN, HID);
    }
    agg1_kernel<<<(N + 7) / 8, 256, 0, stream>>>(xwk1, xr1, offs, spk, bias1, h, N);

    // 3) Layer 2: tables from h @ [W2 | root2]; aggregate + log_softmax -> out
    {
        int total = N * (KS * NCLS + NCLS);
        xw_kernel<<<(total + 255) / 256, 256, 0, stream>>>(h, W2, root2, xwk2, xr2, N, HID, NCLS);
    }
    agg2_kernel<<<(N + 15) / 16, 256, 0, stream>>>(xwk2, xr2, offs, spk, bias2, out, N);
}

// Round 4
// 347.429 us; speedup vs baseline: 1.9302x; 1.7814x over previous
//
#include <hip/hip_runtime.h>
#include <math.h>

// SplineConv x2 (K=4, dim=1, degree=1, mean aggr) + ELU + log_softmax.
// R4: R3 showed random 4B scatter writes back one full 64B line per store
// (WRITE_SIZE 100MB for 6.4MB payload) because all XCDs write everywhere.
// Fix: bucket sort (256 nodes/bucket) with block-owned output regions:
//  - bucket_scatter: LDS tile-sort, bucket-contiguous ~168B runs.
//  - node_sort: one block per bucket; scattered writes span ~32KB ->
//    single-XCD L2 write-combined. Also emits per-node offs[] (kills the
//    serial 50k scan + per-node histogram).
// xw kernels vectorized (float4 register blocking).

#define F_IN   48
#define HID    32
#define NCLS   10
#define KS     4
#define BKT_SH 8               // 256 nodes per bucket
#define TILE   4096            // edges per bucket_scatter block

__device__ inline unsigned short f2bf(float f) {
    unsigned x = __float_as_uint(f);
    unsigned r = x + 0x7FFFu + ((x >> 16) & 1u);  // RNE
    return (unsigned short)(r >> 16);
}
__device__ inline float bf2f(unsigned short u) {
    return __uint_as_float(((unsigned)u) << 16);
}

// ---------- CSR build ----------

__global__ void bucket_hist_kernel(const int* __restrict__ ei, int* __restrict__ bcnt,
                                   int E, int NB) {
    __shared__ int lcnt[256];
    int t = threadIdx.x;
    lcnt[t] = 0;
    __syncthreads();
    int e0 = blockIdx.x * TILE;
    int n = min(TILE, E - e0);
    for (int r = 0; r < TILE / 256; ++r) {
        int i = r * 256 + t;
        if (i < n) atomicAdd(&lcnt[ei[E + e0 + i] >> BKT_SH], 1);
    }
    __syncthreads();
    if (t < NB && lcnt[t] > 0) atomicAdd(&bcnt[t], lcnt[t]);
}

// 1 block, 256 threads: exclusive scan of bcnt -> bbase[0..NB], gcur copy.
__global__ void mini_scan_kernel(const int* __restrict__ bcnt, int* __restrict__ bbase,
                                 int* __restrict__ gcur, int NB) {
    __shared__ int a[256], c[256];
    int t = threadIdx.x;
    int v = (t < NB) ? bcnt[t] : 0;
    a[t] = v; c[t] = v;
    __syncthreads();
    for (int o = 1; o < 256; o <<= 1) {
        int w = (t >= o) ? a[t - o] : 0;
        __syncthreads();
        a[t] += w;
        __syncthreads();
    }
    int ex = a[t] - c[t];
    if (t < NB) { bbase[t] = ex; gcur[t] = ex; }
    if (t == 0) bbase[NB] = a[255];
}

// Tile -> LDS sort by bucket -> bucket-contiguous (payload,dst) records.
__global__ void bucket_scatter_kernel(const int* __restrict__ ei, const float* __restrict__ ea,
                                      int* __restrict__ gcur, uint2* __restrict__ tpd,
                                      int E, int NB) {
    __shared__ unsigned spl[TILE];
    __shared__ unsigned short sdst[TILE];
    __shared__ unsigned short inv[TILE];
    __shared__ int lcnt[256], loff[256], lrank[256], gb[256];
    int t = threadIdx.x;
    lcnt[t] = 0; lrank[t] = 0;
    __syncthreads();
    int e0 = blockIdx.x * TILE;
    int n = min(TILE, E - e0);
    for (int r = 0; r < TILE / 256; ++r) {
        int i = r * 256 + t;
        if (i < n) {
            int e = e0 + i;
            int src = ei[e];
            int dst = ei[E + e];
            float u = ea[e];
            float v = u * (float)(KS - 1);
            float vf = floorf(v);
            int k0 = min(max((int)vf, 0), KS - 1);
            unsigned qf = (unsigned)((v - vf) * 16383.f + 0.5f);  // 14-bit frac
            spl[i] = (unsigned)src | ((unsigned)k0 << 16) | (qf << 18);
            sdst[i] = (unsigned short)dst;
            atomicAdd(&lcnt[dst >> BKT_SH], 1);
        }
    }
    __syncthreads();
    loff[t] = lcnt[t];
    __syncthreads();
    for (int o = 1; o < 256; o <<= 1) {
        int w = (t >= o) ? loff[t - o] : 0;
        __syncthreads();
        loff[t] += w;
        __syncthreads();
    }
    int ex = loff[t] - lcnt[t];
    __syncthreads();
    loff[t] = ex;  // exclusive within-tile bucket offset
    if (t < NB) gb[t] = atomicAdd(&gcur[t], lcnt[t]);
    __syncthreads();
    for (int r = 0; r < TILE / 256; ++r) {
        int i = r * 256 + t;
        if (i < n) {
            int b = sdst[i] >> BKT_SH;
            int p = loff[b] + atomicAdd(&lrank[b], 1);
            inv[p] = (unsigned short)i;
        }
    }
    __syncthreads();
    for (int r = 0; r < TILE / 256; ++r) {
        int j = r * 256 + t;
        if (j < n) {
            int i = inv[j];
            int d = sdst[i];
            int b = d >> BKT_SH;
            int pos = gb[b] + (j - loff[b]);
            tpd[pos] = make_uint2(spl[i], (unsigned)d);
        }
    }
}

// One block per bucket: sort bucket's edges by node, emit spk + offs.
// Scattered writes span ~32KB -> single-XCD L2, write-combined.
__global__ void node_sort_kernel(const uint2* __restrict__ tpd, const int* __restrict__ bbase,
                                 unsigned* __restrict__ spk, int* __restrict__ offs,
                                 int N, int NB) {
    __shared__ int hc[256], hs[256], hr[256];
    int b = blockIdx.x;
    int t = threadIdx.x;
    int nb0 = b << BKT_SH;
    int nb = min(256, N - nb0);
    int base = bbase[b];
    int m = bbase[b + 1] - base;
    hc[t] = 0; hr[t] = 0;
    __syncthreads();
    for (int i = t; i < m; i += 256) atomicAdd(&hc[tpd[base + i].y - nb0], 1);
    __syncthreads();
    hs[t] = hc[t];
    __syncthreads();
    for (int o = 1; o < 256; o <<= 1) {
        int w = (t >= o) ? hs[t - o] : 0;
        __syncthreads();
        hs[t] += w;
        __syncthreads();
    }
    if (t < nb) offs[nb0 + t] = base + (hs[t] - hc[t]);
    if (b == NB - 1 && t == 0) offs[N] = base + m;
    for (int i = t; i < m; i += 256) {
        uint2 rec = tpd[base + i];
        int d = rec.y - nb0;
        int p = (hs[d] - hc[d]) + atomicAdd(&hr[d], 1);
        spk[base + p] = rec.x;
    }
}

// ---------- xw tables ----------

// Layer 1: thread = 1 node x 16 cols (col-group g: 0..7 table, 8..9 root).
__global__ void xw1v_kernel(const float* __restrict__ X, const float* __restrict__ W,
                            const float* __restrict__ R, unsigned short* __restrict__ outk,
                            float* __restrict__ outr, int n) {
    int id = blockIdx.x * blockDim.x + threadIdx.x;
    if (id >= n * 10) return;
    int node = id / 10;
    int g = id - node * 10;
    const float4* X4 = (const float4*)(X + (size_t)node * F_IN);
    const float4* Wf4;
    if (g < 8) {
        int k = g >> 1;
        int o0 = (g & 1) * 16;
        Wf4 = (const float4*)(W + (size_t)k * F_IN * HID + o0);
    } else {
        Wf4 = (const float4*)(R + (g - 8) * 16);
    }
    float4 a0 = {0,0,0,0}, a1 = {0,0,0,0}, a2 = {0,0,0,0}, a3 = {0,0,0,0};
#pragma unroll
    for (int fb = 0; fb < F_IN / 4; ++fb) {
        float4 xv = X4[fb];
#pragma unroll
        for (int j = 0; j < 4; ++j) {
            float s = (j == 0) ? xv.x : (j == 1) ? xv.y : (j == 2) ? xv.z : xv.w;
            const float4* wr = Wf4 + (size_t)(fb * 4 + j) * (HID / 4);
            float4 w0 = wr[0], w1 = wr[1], w2 = wr[2], w3 = wr[3];
            a0.x = fmaf(s, w0.x, a0.x); a0.y = fmaf(s, w0.y, a0.y);
            a0.z = fmaf(s, w0.z, a0.z); a0.w = fmaf(s, w0.w, a0.w);
            a1.x = fmaf(s, w1.x, a1.x); a1.y = fmaf(s, w1.y, a1.y);
            a1.z = fmaf(s, w1.z, a1.z); a1.w = fmaf(s, w1.w, a1.w);
            a2.x = fmaf(s, w2.x, a2.x); a2.y = fmaf(s, w2.y, a2.y);
            a2.z = fmaf(s, w2.z, a2.z); a2.w = fmaf(s, w2.w, a2.w);
            a3.x = fmaf(s, w3.x, a3.x); a3.y = fmaf(s, w3.y, a3.y);
            a3.z = fmaf(s, w3.z, a3.z); a3.w = fmaf(s, w3.w, a3.w);
        }
    }
    if (g < 8) {
        uint4 u0, u1;
        u0.x = f2bf(a0.x) | ((unsigned)f2bf(a0.y) << 16);
        u0.y = f2bf(a0.z) | ((unsigned)f2bf(a0.w) << 16);
        u0.z = f2bf(a1.x) | ((unsigned)f2bf(a1.y) << 16);
        u0.w = f2bf(a1.z) | ((unsigned)f2bf(a1.w) << 16);
        u1.x = f2bf(a2.x) | ((unsigned)f2bf(a2.y) << 16);
        u1.y = f2bf(a2.z) | ((unsigned)f2bf(a2.w) << 16);
        u1.z = f2bf(a3.x) | ((unsigned)f2bf(a3.y) << 16);
        u1.w = f2bf(a3.z) | ((unsigned)f2bf(a3.w) << 16);
        uint4* dst = (uint4*)(outk + (size_t)node * (KS * HID) + g * 16);
        dst[0] = u0; dst[1] = u1;
    } else {
        float4* dst = (float4*)(outr + (size_t)node * HID + (g - 8) * 16);
        dst[0] = a0; dst[1] = a1; dst[2] = a2; dst[3] = a3;
    }
}

// Layer 2: thread = 1 node x 2 cols (pair p: 0..19 table, 20..24 root).
__global__ void xw2v_kernel(const float* __restrict__ H, const float* __restrict__ W,
                            const float* __restrict__ R, unsigned short* __restrict__ outk,
                            float* __restrict__ outr, int n) {
    int id = blockIdx.x * blockDim.x + threadIdx.x;
    if (id >= n * 25) return;
    int node = id / 25;
    int p = id - node * 25;
    int col = 2 * p;
    const float4* H4 = (const float4*)(H + (size_t)node * HID);
    const float* base;
    if (col < KS * NCLS) {
        int k = col / NCLS;
        base = W + (size_t)k * HID * NCLS + (col - k * NCLS);
    } else {
        base = R + (col - KS * NCLS);
    }
    float ax = 0.f, ay = 0.f;
#pragma unroll
    for (int fb = 0; fb < HID / 4; ++fb) {
        float4 xv = H4[fb];
#pragma unroll
        for (int j = 0; j < 4; ++j) {
            float s = (j == 0) ? xv.x : (j == 1) ? xv.y : (j == 2) ? xv.z : xv.w;
            const float* wr = base + (size_t)(fb * 4 + j) * NCLS;
            float2 wv = *(const float2*)wr;
            ax = fmaf(s, wv.x, ax);
            ay = fmaf(s, wv.y, ay);
        }
    }
    if (col < KS * NCLS) {
        unsigned u = f2bf(ax) | ((unsigned)f2bf(ay) << 16);
        *(unsigned*)(outk + (size_t)node * (KS * NCLS) + col) = u;
    } else {
        *(float2*)(outr + (size_t)node * NCLS + (col - KS * NCLS)) = make_float2(ax, ay);
    }
}

// ---------- aggregation (unchanged from R3) ----------

__device__ inline float interp32(const unsigned short* __restrict__ xwk, unsigned p, int c) {
    int src = p & 0xFFFF;
    int k0 = (p >> 16) & 3;
    int k1 = min(k0 + 1, KS - 1);
    float fr = (float)(p >> 18) * (1.f / 16383.f);
    const unsigned short* row = xwk + (size_t)src * (KS * HID);
    float v0 = bf2f(row[k0 * HID + c]);
    float v1 = bf2f(row[k1 * HID + c]);
    return fmaf(fr, v1 - v0, v0);
}

__global__ void agg1_kernel(const unsigned short* __restrict__ xwk,
                            const float* __restrict__ xroot,
                            const int* __restrict__ offs, const unsigned* __restrict__ spk,
                            const float* __restrict__ bias, float* __restrict__ h, int n) {
    int c = threadIdx.x & 31;
    int node = blockIdx.x * 8 + (threadIdx.x >> 5);
    if (node >= n) return;
    int beg = offs[node];
    int end = offs[node + 1];
    float s0 = 0.f, s1 = 0.f;
    int e = beg;
    for (; e + 2 <= end; e += 2) {
        unsigned p0 = spk[e];
        unsigned p1 = spk[e + 1];
        s0 += interp32(xwk, p0, c);
        s1 += interp32(xwk, p1, c);
    }
    if (e < end) s0 += interp32(xwk, spk[e], c);
    float sum = s0 + s1;
    int deg = end - beg;
    float m = sum / (float)(deg > 0 ? deg : 1);
    float o = m + xroot[(size_t)node * HID + c] + bias[c];
    h[(size_t)node * HID + c] = (o > 0.f) ? o : expm1f(o);
}

__device__ inline float interp10(const unsigned short* __restrict__ xwk, unsigned p, int cc) {
    int src = p & 0xFFFF;
    int k0 = (p >> 16) & 3;
    int k1 = min(k0 + 1, KS - 1);
    float fr = (float)(p >> 18) * (1.f / 16383.f);
    const unsigned short* row = xwk + (size_t)src * (KS * NCLS);
    float v0 = bf2f(row[k0 * NCLS + cc]);
    float v1 = bf2f(row[k1 * NCLS + cc]);
    return fmaf(fr, v1 - v0, v0);
}

__global__ void agg2_kernel(const unsigned short* __restrict__ xwk,
                            const float* __restrict__ xroot,
                            const int* __restrict__ offs, const unsigned* __restrict__ spk,
                            const float* __restrict__ bias, float* __restrict__ out, int n) {
    int c = threadIdx.x & 15;
    int node = blockIdx.x * 16 + (threadIdx.x >> 4);
    if (node >= n) return;
    int cc = min(c, NCLS - 1);
    int beg = offs[node];
    int end = offs[node + 1];
    float s0 = 0.f, s1 = 0.f;
    int e = beg;
    for (; e + 2 <= end; e += 2) {
        unsigned p0 = spk[e];
        unsigned p1 = spk[e + 1];
        s0 += interp10(xwk, p0, cc);
        s1 += interp10(xwk, p1, cc);
    }
    if (e < end) s0 += interp10(xwk, spk[e], cc);
    float sum = s0 + s1;
    int deg = end - beg;
    float m = sum / (float)(deg > 0 ? deg : 1);
    float logit = m + xroot[(size_t)node * NCLS + cc] + bias[cc];
    bool active = (c < NCLS);
    float mx = active ? logit : -INFINITY;
#pragma unroll
    for (int msk = 1; msk < 16; msk <<= 1) mx = fmaxf(mx, __shfl_xor(mx, msk, 16));
    float ex = active ? expf(logit - mx) : 0.f;
    float s = ex;
#pragma unroll
    for (int msk = 1; msk < 16; msk <<= 1) s += __shfl_xor(s, msk, 16);
    if (active) out[(size_t)node * NCLS + c] = (logit - mx) - logf(s);
}

extern "C" void kernel_launch(void* const* d_in, const int* in_sizes, int n_in,
                              void* d_out, int out_size, void* d_ws, size_t ws_size,
                              hipStream_t stream) {
    const float* x       = (const float*)d_in[0];
    const int*   ei      = (const int*)d_in[1];
    const float* ea      = (const float*)d_in[2];
    const float* W1      = (const float*)d_in[3];
    const float* root1   = (const float*)d_in[4];
    const float* bias1   = (const float*)d_in[5];
    const float* W2      = (const float*)d_in[6];
    const float* root2   = (const float*)d_in[7];
    const float* bias2   = (const float*)d_in[8];
    float* out = (float*)d_out;

    const int N = in_sizes[0] / F_IN;      // 50000
    const int E = in_sizes[2];             // 1600000
    const int NB = (N + 255) >> BKT_SH;    // 196

    // Workspace (256B-aligned). tpd aliases xwk1 (tpd dead before xw1v runs).
    char* base = (char*)d_ws;
    size_t off = 0;
    auto alloc = [&](size_t bytes) {
        char* p = base + off;
        off = (off + bytes + 255) & ~(size_t)255;
        return (void*)p;
    };
    unsigned short* xwk1 = (unsigned short*)alloc((size_t)N * KS * HID * 2); // 12.8 MB
    float* xr1           = (float*)alloc((size_t)N * HID * 4);               // 6.4 MB
    float* h             = (float*)alloc((size_t)N * HID * 4);               // 6.4 MB
    int* offs            = (int*)alloc(((size_t)N + 1) * 4);
    int* bcnt            = (int*)alloc((size_t)NB * 4);
    int* bbase           = (int*)alloc(((size_t)NB + 1) * 4);
    int* gcur            = (int*)alloc((size_t)NB * 4);
    unsigned* spk        = (unsigned*)alloc((size_t)E * 4);                  // 6.4 MB
    uint2* tpd           = (uint2*)xwk1;  // E*8 = 12.8 MB fits xwk1 region
    unsigned short* xwk2 = xwk1;          // layer-2 tables alias layer-1
    float* xr2           = xr1;
    if (ws_size < off) return;

    int ebk = (E + TILE - 1) / TILE;  // 391

    hipMemsetAsync(bcnt, 0, (size_t)NB * 4, stream);
    bucket_hist_kernel<<<ebk, 256, 0, stream>>>(ei, bcnt, E, NB);
    mini_scan_kernel<<<1, 256, 0, stream>>>(bcnt, bbase, gcur, NB);
    bucket_scatter_kernel<<<ebk, 256, 0, stream>>>(ei, ea, gcur, tpd, E, NB);
    node_sort_kernel<<<NB, 256, 0, stream>>>(tpd, bbase, spk, offs, N, NB);
    // xw1v must come after node_sort (tpd aliases xwk1)
    xw1v_kernel<<<(N * 10 + 255) / 256, 256, 0, stream>>>(x, W1, root1, xwk1, xr1, N);
    agg1_kernel<<<(N + 7) / 8, 256, 0, stream>>>(xwk1, xr1, offs, spk, bias1, h, N);
    xw2v_kernel<<<(N * 25 + 255) / 256, 256, 0, stream>>>(h, W2, root2, xwk2, xr2, N);
    agg2_kernel<<<(N + 15) / 16, 256, 0, stream>>>(xwk2, xr2, offs, spk, bias2, out, N);
}

// Round 5
// 271.346 us; speedup vs baseline: 2.4714x; 1.2804x over previous
//
#include <hip/hip_runtime.h>
#include <math.h>

// SplineConv x2 (K=4, dim=1, degree=1, mean aggr) + ELU + log_softmax.
// R5: R4's xw1v was latency-bound (96us, VALUBusy 13%) on per-thread L1
// re-reads of W (30.7KB thrashing 32KB L1). Fix: stage W in LDS once per
// block; register-block 2 nodes x 4 cols per thread (ds_read_b128 per k).
// CSR build (bucket sort, block-owned output regions) and agg kernels
// unchanged from R4.

#define F_IN   48
#define HID    32
#define NCLS   10
#define KS     4
#define BKT_SH 8               // 256 nodes per bucket
#define TILE   4096            // edges per bucket_scatter block

__device__ inline unsigned short f2bf(float f) {
    unsigned x = __float_as_uint(f);
    unsigned r = x + 0x7FFFu + ((x >> 16) & 1u);  // RNE
    return (unsigned short)(r >> 16);
}
__device__ inline float bf2f(unsigned short u) {
    return __uint_as_float(((unsigned)u) << 16);
}

// ---------- CSR build ----------

__global__ void bucket_hist_kernel(const int* __restrict__ ei, int* __restrict__ bcnt,
                                   int E, int NB) {
    __shared__ int lcnt[256];
    int t = threadIdx.x;
    lcnt[t] = 0;
    __syncthreads();
    int e0 = blockIdx.x * TILE;
    int n = min(TILE, E - e0);
    for (int r = 0; r < TILE / 256; ++r) {
        int i = r * 256 + t;
        if (i < n) atomicAdd(&lcnt[ei[E + e0 + i] >> BKT_SH], 1);
    }
    __syncthreads();
    if (t < NB && lcnt[t] > 0) atomicAdd(&bcnt[t], lcnt[t]);
}

__global__ void mini_scan_kernel(const int* __restrict__ bcnt, int* __restrict__ bbase,
                                 int* __restrict__ gcur, int NB) {
    __shared__ int a[256], c[256];
    int t = threadIdx.x;
    int v = (t < NB) ? bcnt[t] : 0;
    a[t] = v; c[t] = v;
    __syncthreads();
    for (int o = 1; o < 256; o <<= 1) {
        int w = (t >= o) ? a[t - o] : 0;
        __syncthreads();
        a[t] += w;
        __syncthreads();
    }
    int ex = a[t] - c[t];
    if (t < NB) { bbase[t] = ex; gcur[t] = ex; }
    if (t == 0) bbase[NB] = a[255];
}

__global__ void bucket_scatter_kernel(const int* __restrict__ ei, const float* __restrict__ ea,
                                      int* __restrict__ gcur, uint2* __restrict__ tpd,
                                      int E, int NB) {
    __shared__ unsigned spl[TILE];
    __shared__ unsigned short sdst[TILE];
    __shared__ unsigned short inv[TILE];
    __shared__ int lcnt[256], loff[256], lrank[256], gb[256];
    int t = threadIdx.x;
    lcnt[t] = 0; lrank[t] = 0;
    __syncthreads();
    int e0 = blockIdx.x * TILE;
    int n = min(TILE, E - e0);
    for (int r = 0; r < TILE / 256; ++r) {
        int i = r * 256 + t;
        if (i < n) {
            int e = e0 + i;
            int src = ei[e];
            int dst = ei[E + e];
            float u = ea[e];
            float v = u * (float)(KS - 1);
            float vf = floorf(v);
            int k0 = min(max((int)vf, 0), KS - 1);
            unsigned qf = (unsigned)((v - vf) * 16383.f + 0.5f);  // 14-bit frac
            spl[i] = (unsigned)src | ((unsigned)k0 << 16) | (qf << 18);
            sdst[i] = (unsigned short)dst;
            atomicAdd(&lcnt[dst >> BKT_SH], 1);
        }
    }
    __syncthreads();
    loff[t] = lcnt[t];
    __syncthreads();
    for (int o = 1; o < 256; o <<= 1) {
        int w = (t >= o) ? loff[t - o] : 0;
        __syncthreads();
        loff[t] += w;
        __syncthreads();
    }
    int ex = loff[t] - lcnt[t];
    __syncthreads();
    loff[t] = ex;
    if (t < NB) gb[t] = atomicAdd(&gcur[t], lcnt[t]);
    __syncthreads();
    for (int r = 0; r < TILE / 256; ++r) {
        int i = r * 256 + t;
        if (i < n) {
            int b = sdst[i] >> BKT_SH;
            int p = loff[b] + atomicAdd(&lrank[b], 1);
            inv[p] = (unsigned short)i;
        }
    }
    __syncthreads();
    for (int r = 0; r < TILE / 256; ++r) {
        int j = r * 256 + t;
        if (j < n) {
            int i = inv[j];
            int d = sdst[i];
            int b = d >> BKT_SH;
            int pos = gb[b] + (j - loff[b]);
            tpd[pos] = make_uint2(spl[i], (unsigned)d);
        }
    }
}

__global__ void node_sort_kernel(const uint2* __restrict__ tpd, const int* __restrict__ bbase,
                                 unsigned* __restrict__ spk, int* __restrict__ offs,
                                 int N, int NB) {
    __shared__ int hc[256], hs[256], hr[256];
    int b = blockIdx.x;
    int t = threadIdx.x;
    int nb0 = b << BKT_SH;
    int nb = min(256, N - nb0);
    int base = bbase[b];
    int m = bbase[b + 1] - base;
    hc[t] = 0; hr[t] = 0;
    __syncthreads();
    for (int i = t; i < m; i += 256) atomicAdd(&hc[tpd[base + i].y - nb0], 1);
    __syncthreads();
    hs[t] = hc[t];
    __syncthreads();
    for (int o = 1; o < 256; o <<= 1) {
        int w = (t >= o) ? hs[t - o] : 0;
        __syncthreads();
        hs[t] += w;
        __syncthreads();
    }
    if (t < nb) offs[nb0 + t] = base + (hs[t] - hc[t]);
    if (b == NB - 1 && t == 0) offs[N] = base + m;
    for (int i = t; i < m; i += 256) {
        uint2 rec = tpd[base + i];
        int d = rec.y - nb0;
        int p = (hs[d] - hc[d]) + atomicAdd(&hr[d], 1);
        spk[base + p] = rec.x;
    }
}

// ---------- xw tables (LDS-staged W, register-blocked) ----------

// Layer 1: block 320 thr = 8 node-pairs x 40 colgroups. lw[f][col], col =
// k*32+o for col<128, 128+o for root. Thread: 2 nodes x 4 cols.
__global__ __launch_bounds__(320) void xw1_kernel(
        const float* __restrict__ X, const float* __restrict__ W,
        const float* __restrict__ R, unsigned short* __restrict__ outk,
        float* __restrict__ outr, int n) {
    __shared__ float lw[48 * 160];
    int t = threadIdx.x;
    for (int i = t; i < 48 * 160; i += 320) {
        int f = i / 160;
        int col = i - f * 160;
        lw[i] = (col < 128) ? W[(size_t)(col >> 5) * (48 * 32) + f * 32 + (col & 31)]
                            : R[f * 32 + (col - 128)];
    }
    __syncthreads();
    int g = t % 40;      // colgroup (4 cols)
    int lp = t / 40;     // local pair 0..7
    int n0 = (blockIdx.x * 8 + lp) * 2;
    if (n0 + 1 >= n) return;  // N even; full blocks only
    const float4* X0 = (const float4*)(X + (size_t)n0 * F_IN);
    const float4* X1 = (const float4*)(X + (size_t)(n0 + 1) * F_IN);
    float4 x0[12], x1[12];
#pragma unroll
    for (int i = 0; i < 12; ++i) { x0[i] = X0[i]; x1[i] = X1[i]; }
    const float4* lw4 = (const float4*)lw;  // lw4[f*40 + g]
    float4 a0 = {0,0,0,0}, a1 = {0,0,0,0};
#pragma unroll
    for (int fb = 0; fb < 12; ++fb) {
        float4 v0 = x0[fb], v1 = x1[fb];
#pragma unroll
        for (int j = 0; j < 4; ++j) {
            float s0 = (j == 0) ? v0.x : (j == 1) ? v0.y : (j == 2) ? v0.z : v0.w;
            float s1 = (j == 0) ? v1.x : (j == 1) ? v1.y : (j == 2) ? v1.z : v1.w;
            float4 w = lw4[(fb * 4 + j) * 40 + g];
            a0.x = fmaf(s0, w.x, a0.x); a0.y = fmaf(s0, w.y, a0.y);
            a0.z = fmaf(s0, w.z, a0.z); a0.w = fmaf(s0, w.w, a0.w);
            a1.x = fmaf(s1, w.x, a1.x); a1.y = fmaf(s1, w.y, a1.y);
            a1.z = fmaf(s1, w.z, a1.z); a1.w = fmaf(s1, w.w, a1.w);
        }
    }
    if (g < 32) {  // table cols 4g..4g+3 -> bf16
        uint2 u0, u1;
        u0.x = f2bf(a0.x) | ((unsigned)f2bf(a0.y) << 16);
        u0.y = f2bf(a0.z) | ((unsigned)f2bf(a0.w) << 16);
        u1.x = f2bf(a1.x) | ((unsigned)f2bf(a1.y) << 16);
        u1.y = f2bf(a1.z) | ((unsigned)f2bf(a1.w) << 16);
        *(uint2*)(outk + (size_t)n0 * (KS * HID) + g * 4) = u0;
        *(uint2*)(outk + (size_t)(n0 + 1) * (KS * HID) + g * 4) = u1;
    } else {       // root cols
        int o = 4 * g - 128;
        *(float4*)(outr + (size_t)n0 * HID + o) = a0;
        *(float4*)(outr + (size_t)(n0 + 1) * HID + o) = a1;
    }
}

// Layer 2: lw2[f][col], col = k*10+o (<40) else 40+o root. Thread: 2 nodes x
// 2 cols (25 col-pairs); grid-stride over (n/2)*25 items.
__global__ void xw2_kernel(const float* __restrict__ H, const float* __restrict__ W,
                           const float* __restrict__ R, unsigned short* __restrict__ outk,
                           float* __restrict__ outr, int n) {
    __shared__ float lw2[32 * 50];
    int t = threadIdx.x;
    for (int i = t; i < 32 * 50; i += 256) {
        int f = i / 50;
        int col = i - f * 50;
        lw2[i] = (col < 40) ? W[(size_t)(col / 10) * (32 * 10) + f * 10 + (col % 10)]
                            : R[f * 10 + (col - 40)];
    }
    __syncthreads();
    int total = (n / 2) * 25;
    int id = blockIdx.x * blockDim.x + t;
    if (id >= total) return;
    int p = id % 25;          // col-pair
    int pr = id / 25;
    int n0 = 2 * pr;
    const float4* H0 = (const float4*)(H + (size_t)n0 * HID);
    const float4* H1 = (const float4*)(H + (size_t)(n0 + 1) * HID);
    float4 h0[8], h1[8];
#pragma unroll
    for (int i = 0; i < 8; ++i) { h0[i] = H0[i]; h1[i] = H1[i]; }
    const float2* lwp = (const float2*)lw2;  // lwp[f*25 + p]
    float ax0 = 0.f, ay0 = 0.f, ax1 = 0.f, ay1 = 0.f;
#pragma unroll
    for (int fb = 0; fb < 8; ++fb) {
        float4 v0 = h0[fb], v1 = h1[fb];
#pragma unroll
        for (int j = 0; j < 4; ++j) {
            float s0 = (j == 0) ? v0.x : (j == 1) ? v0.y : (j == 2) ? v0.z : v0.w;
            float s1 = (j == 0) ? v1.x : (j == 1) ? v1.y : (j == 2) ? v1.z : v1.w;
            float2 w = lwp[(fb * 4 + j) * 25 + p];
            ax0 = fmaf(s0, w.x, ax0); ay0 = fmaf(s0, w.y, ay0);
            ax1 = fmaf(s1, w.x, ax1); ay1 = fmaf(s1, w.y, ay1);
        }
    }
    int col = 2 * p;
    if (col < KS * NCLS) {
        *(unsigned*)(outk + (size_t)n0 * (KS * NCLS) + col) =
            f2bf(ax0) | ((unsigned)f2bf(ay0) << 16);
        *(unsigned*)(outk + (size_t)(n0 + 1) * (KS * NCLS) + col) =
            f2bf(ax1) | ((unsigned)f2bf(ay1) << 16);
    } else {
        int o = col - KS * NCLS;
        *(float2*)(outr + (size_t)n0 * NCLS + o) = make_float2(ax0, ay0);
        *(float2*)(outr + (size_t)(n0 + 1) * NCLS + o) = make_float2(ax1, ay1);
    }
}

// ---------- aggregation (unchanged) ----------

__device__ inline float interp32(const unsigned short* __restrict__ xwk, unsigned p, int c) {
    int src = p & 0xFFFF;
    int k0 = (p >> 16) & 3;
    int k1 = min(k0 + 1, KS - 1);
    float fr = (float)(p >> 18) * (1.f / 16383.f);
    const unsigned short* row = xwk + (size_t)src * (KS * HID);
    float v0 = bf2f(row[k0 * HID + c]);
    float v1 = bf2f(row[k1 * HID + c]);
    return fmaf(fr, v1 - v0, v0);
}

__global__ void agg1_kernel(const unsigned short* __restrict__ xwk,
                            const float* __restrict__ xroot,
                            const int* __restrict__ offs, const unsigned* __restrict__ spk,
                            const float* __restrict__ bias, float* __restrict__ h, int n) {
    int c = threadIdx.x & 31;
    int node = blockIdx.x * 8 + (threadIdx.x >> 5);
    if (node >= n) return;
    int beg = offs[node];
    int end = offs[node + 1];
    float s0 = 0.f, s1 = 0.f;
    int e = beg;
    for (; e + 2 <= end; e += 2) {
        unsigned p0 = spk[e];
        unsigned p1 = spk[e + 1];
        s0 += interp32(xwk, p0, c);
        s1 += interp32(xwk, p1, c);
    }
    if (e < end) s0 += interp32(xwk, spk[e], c);
    float sum = s0 + s1;
    int deg = end - beg;
    float m = sum / (float)(deg > 0 ? deg : 1);
    float o = m + xroot[(size_t)node * HID + c] + bias[c];
    h[(size_t)node * HID + c] = (o > 0.f) ? o : expm1f(o);
}

__device__ inline float interp10(const unsigned short* __restrict__ xwk, unsigned p, int cc) {
    int src = p & 0xFFFF;
    int k0 = (p >> 16) & 3;
    int k1 = min(k0 + 1, KS - 1);
    float fr = (float)(p >> 18) * (1.f / 16383.f);
    const unsigned short* row = xwk + (size_t)src * (KS * NCLS);
    float v0 = bf2f(row[k0 * NCLS + cc]);
    float v1 = bf2f(row[k1 * NCLS + cc]);
    return fmaf(fr, v1 - v0, v0);
}

__global__ void agg2_kernel(const unsigned short* __restrict__ xwk,
                            const float* __restrict__ xroot,
                            const int* __restrict__ offs, const unsigned* __restrict__ spk,
                            const float* __restrict__ bias, float* __restrict__ out, int n) {
    int c = threadIdx.x & 15;
    int node = blockIdx.x * 16 + (threadIdx.x >> 4);
    if (node >= n) return;
    int cc = min(c, NCLS - 1);
    int beg = offs[node];
    int end = offs[node + 1];
    float s0 = 0.f, s1 = 0.f;
    int e = beg;
    for (; e + 2 <= end; e += 2) {
        unsigned p0 = spk[e];
        unsigned p1 = spk[e + 1];
        s0 += interp10(xwk, p0, cc);
        s1 += interp10(xwk, p1, cc);
    }
    if (e < end) s0 += interp10(xwk, spk[e], cc);
    float sum = s0 + s1;
    int deg = end - beg;
    float m = sum / (float)(deg > 0 ? deg : 1);
    float logit = m + xroot[(size_t)node * NCLS + cc] + bias[cc];
    bool active = (c < NCLS);
    float mx = active ? logit : -INFINITY;
#pragma unroll
    for (int msk = 1; msk < 16; msk <<= 1) mx = fmaxf(mx, __shfl_xor(mx, msk, 16));
    float ex = active ? expf(logit - mx) : 0.f;
    float s = ex;
#pragma unroll
    for (int msk = 1; msk < 16; msk <<= 1) s += __shfl_xor(s, msk, 16);
    if (active) out[(size_t)node * NCLS + c] = (logit - mx) - logf(s);
}

extern "C" void kernel_launch(void* const* d_in, const int* in_sizes, int n_in,
                              void* d_out, int out_size, void* d_ws, size_t ws_size,
                              hipStream_t stream) {
    const float* x       = (const float*)d_in[0];
    const int*   ei      = (const int*)d_in[1];
    const float* ea      = (const float*)d_in[2];
    const float* W1      = (const float*)d_in[3];
    const float* root1   = (const float*)d_in[4];
    const float* bias1   = (const float*)d_in[5];
    const float* W2      = (const float*)d_in[6];
    const float* root2   = (const float*)d_in[7];
    const float* bias2   = (const float*)d_in[8];
    float* out = (float*)d_out;

    const int N = in_sizes[0] / F_IN;      // 50000
    const int E = in_sizes[2];             // 1600000
    const int NB = (N + 255) >> BKT_SH;    // 196

    char* base = (char*)d_ws;
    size_t off = 0;
    auto alloc = [&](size_t bytes) {
        char* p = base + off;
        off = (off + bytes + 255) & ~(size_t)255;
        return (void*)p;
    };
    unsigned short* xwk1 = (unsigned short*)alloc((size_t)N * KS * HID * 2); // 12.8 MB
    float* xr1           = (float*)alloc((size_t)N * HID * 4);               // 6.4 MB
    float* h             = (float*)alloc((size_t)N * HID * 4);               // 6.4 MB
    int* offs            = (int*)alloc(((size_t)N + 1) * 4);
    int* bcnt            = (int*)alloc((size_t)NB * 4);
    int* bbase           = (int*)alloc(((size_t)NB + 1) * 4);
    int* gcur            = (int*)alloc((size_t)NB * 4);
    unsigned* spk        = (unsigned*)alloc((size_t)E * 4);                  // 6.4 MB
    uint2* tpd           = (uint2*)xwk1;  // aliases xwk1 (dead before xw1)
    unsigned short* xwk2 = xwk1;
    float* xr2           = xr1;
    if (ws_size < off) return;

    int ebk = (E + TILE - 1) / TILE;

    hipMemsetAsync(bcnt, 0, (size_t)NB * 4, stream);
    bucket_hist_kernel<<<ebk, 256, 0, stream>>>(ei, bcnt, E, NB);
    mini_scan_kernel<<<1, 256, 0, stream>>>(bcnt, bbase, gcur, NB);
    bucket_scatter_kernel<<<ebk, 256, 0, stream>>>(ei, ea, gcur, tpd, E, NB);
    node_sort_kernel<<<NB, 256, 0, stream>>>(tpd, bbase, spk, offs, N, NB);
    // xw1 after node_sort (tpd aliases xwk1)
    xw1_kernel<<<(N + 15) / 16, 320, 0, stream>>>(x, W1, root1, xwk1, xr1, N);
    agg1_kernel<<<(N + 7) / 8, 256, 0, stream>>>(xwk1, xr1, offs, spk, bias1, h, N);
    {
        int total = (N / 2) * 25;
        xw2_kernel<<<(total + 255) / 256, 256, 0, stream>>>(h, W2, root2, xwk2, xr2, N);
    }
    agg2_kernel<<<(N + 15) / 16, 256, 0, stream>>>(xwk2, xr2, offs, spk, bias2, out, N);
}

// Round 6
// 269.585 us; speedup vs baseline: 2.4875x; 1.0065x over previous
//
#include <hip/hip_runtime.h>
#include <math.h>

// SplineConv x2 (K=4, dim=1, degree=1, mean aggr) + ELU + log_softmax.
// R6: agg kernels were latency-bound (agg1 60us, 1.9TB/s, VALUBusy 43%):
// only 2 edges in flight per 32-lane group. Now a full wave owns one node,
// lanes = channel x edge-parity, each parity unrolled 2x -> 4 edges / 8
// gather loads in flight, serial chain deg/4. Cross-half shfl_xor merge.
// CSR build (bucket sort) + LDS-staged xw kernels unchanged from R5.

#define F_IN   48
#define HID    32
#define NCLS   10
#define KS     4
#define BKT_SH 8               // 256 nodes per bucket
#define TILE   4096            // edges per bucket_scatter block

__device__ inline unsigned short f2bf(float f) {
    unsigned x = __float_as_uint(f);
    unsigned r = x + 0x7FFFu + ((x >> 16) & 1u);  // RNE
    return (unsigned short)(r >> 16);
}
__device__ inline float bf2f(unsigned short u) {
    return __uint_as_float(((unsigned)u) << 16);
}

// ---------- CSR build ----------

__global__ void bucket_hist_kernel(const int* __restrict__ ei, int* __restrict__ bcnt,
                                   int E, int NB) {
    __shared__ int lcnt[256];
    int t = threadIdx.x;
    lcnt[t] = 0;
    __syncthreads();
    int e0 = blockIdx.x * TILE;
    int n = min(TILE, E - e0);
    for (int r = 0; r < TILE / 256; ++r) {
        int i = r * 256 + t;
        if (i < n) atomicAdd(&lcnt[ei[E + e0 + i] >> BKT_SH], 1);
    }
    __syncthreads();
    if (t < NB && lcnt[t] > 0) atomicAdd(&bcnt[t], lcnt[t]);
}

__global__ void mini_scan_kernel(const int* __restrict__ bcnt, int* __restrict__ bbase,
                                 int* __restrict__ gcur, int NB) {
    __shared__ int a[256], c[256];
    int t = threadIdx.x;
    int v = (t < NB) ? bcnt[t] : 0;
    a[t] = v; c[t] = v;
    __syncthreads();
    for (int o = 1; o < 256; o <<= 1) {
        int w = (t >= o) ? a[t - o] : 0;
        __syncthreads();
        a[t] += w;
        __syncthreads();
    }
    int ex = a[t] - c[t];
    if (t < NB) { bbase[t] = ex; gcur[t] = ex; }
    if (t == 0) bbase[NB] = a[255];
}

__global__ void bucket_scatter_kernel(const int* __restrict__ ei, const float* __restrict__ ea,
                                      int* __restrict__ gcur, uint2* __restrict__ tpd,
                                      int E, int NB) {
    __shared__ unsigned spl[TILE];
    __shared__ unsigned short sdst[TILE];
    __shared__ unsigned short inv[TILE];
    __shared__ int lcnt[256], loff[256], lrank[256], gb[256];
    int t = threadIdx.x;
    lcnt[t] = 0; lrank[t] = 0;
    __syncthreads();
    int e0 = blockIdx.x * TILE;
    int n = min(TILE, E - e0);
    for (int r = 0; r < TILE / 256; ++r) {
        int i = r * 256 + t;
        if (i < n) {
            int e = e0 + i;
            int src = ei[e];
            int dst = ei[E + e];
            float u = ea[e];
            float v = u * (float)(KS - 1);
            float vf = floorf(v);
            int k0 = min(max((int)vf, 0), KS - 1);
            unsigned qf = (unsigned)((v - vf) * 16383.f + 0.5f);  // 14-bit frac
            spl[i] = (unsigned)src | ((unsigned)k0 << 16) | (qf << 18);
            sdst[i] = (unsigned short)dst;
            atomicAdd(&lcnt[dst >> BKT_SH], 1);
        }
    }
    __syncthreads();
    loff[t] = lcnt[t];
    __syncthreads();
    for (int o = 1; o < 256; o <<= 1) {
        int w = (t >= o) ? loff[t - o] : 0;
        __syncthreads();
        loff[t] += w;
        __syncthreads();
    }
    int ex = loff[t] - lcnt[t];
    __syncthreads();
    loff[t] = ex;
    if (t < NB) gb[t] = atomicAdd(&gcur[t], lcnt[t]);
    __syncthreads();
    for (int r = 0; r < TILE / 256; ++r) {
        int i = r * 256 + t;
        if (i < n) {
            int b = sdst[i] >> BKT_SH;
            int p = loff[b] + atomicAdd(&lrank[b], 1);
            inv[p] = (unsigned short)i;
        }
    }
    __syncthreads();
    for (int r = 0; r < TILE / 256; ++r) {
        int j = r * 256 + t;
        if (j < n) {
            int i = inv[j];
            int d = sdst[i];
            int b = d >> BKT_SH;
            int pos = gb[b] + (j - loff[b]);
            tpd[pos] = make_uint2(spl[i], (unsigned)d);
        }
    }
}

__global__ void node_sort_kernel(const uint2* __restrict__ tpd, const int* __restrict__ bbase,
                                 unsigned* __restrict__ spk, int* __restrict__ offs,
                                 int N, int NB) {
    __shared__ int hc[256], hs[256], hr[256];
    int b = blockIdx.x;
    int t = threadIdx.x;
    int nb0 = b << BKT_SH;
    int nb = min(256, N - nb0);
    int base = bbase[b];
    int m = bbase[b + 1] - base;
    hc[t] = 0; hr[t] = 0;
    __syncthreads();
    for (int i = t; i < m; i += 256) atomicAdd(&hc[tpd[base + i].y - nb0], 1);
    __syncthreads();
    hs[t] = hc[t];
    __syncthreads();
    for (int o = 1; o < 256; o <<= 1) {
        int w = (t >= o) ? hs[t - o] : 0;
        __syncthreads();
        hs[t] += w;
        __syncthreads();
    }
    if (t < nb) offs[nb0 + t] = base + (hs[t] - hc[t]);
    if (b == NB - 1 && t == 0) offs[N] = base + m;
    for (int i = t; i < m; i += 256) {
        uint2 rec = tpd[base + i];
        int d = rec.y - nb0;
        int p = (hs[d] - hc[d]) + atomicAdd(&hr[d], 1);
        spk[base + p] = rec.x;
    }
}

// ---------- xw tables (LDS-staged W, register-blocked) ----------

__global__ __launch_bounds__(320) void xw1_kernel(
        const float* __restrict__ X, const float* __restrict__ W,
        const float* __restrict__ R, unsigned short* __restrict__ outk,
        float* __restrict__ outr, int n) {
    __shared__ float lw[48 * 160];
    int t = threadIdx.x;
    for (int i = t; i < 48 * 160; i += 320) {
        int f = i / 160;
        int col = i - f * 160;
        lw[i] = (col < 128) ? W[(size_t)(col >> 5) * (48 * 32) + f * 32 + (col & 31)]
                            : R[f * 32 + (col - 128)];
    }
    __syncthreads();
    int g = t % 40;      // colgroup (4 cols)
    int lp = t / 40;     // local pair 0..7
    int n0 = (blockIdx.x * 8 + lp) * 2;
    if (n0 + 1 >= n) return;
    const float4* X0 = (const float4*)(X + (size_t)n0 * F_IN);
    const float4* X1 = (const float4*)(X + (size_t)(n0 + 1) * F_IN);
    float4 x0[12], x1[12];
#pragma unroll
    for (int i = 0; i < 12; ++i) { x0[i] = X0[i]; x1[i] = X1[i]; }
    const float4* lw4 = (const float4*)lw;  // lw4[f*40 + g]
    float4 a0 = {0,0,0,0}, a1 = {0,0,0,0};
#pragma unroll
    for (int fb = 0; fb < 12; ++fb) {
        float4 v0 = x0[fb], v1 = x1[fb];
#pragma unroll
        for (int j = 0; j < 4; ++j) {
            float s0 = (j == 0) ? v0.x : (j == 1) ? v0.y : (j == 2) ? v0.z : v0.w;
            float s1 = (j == 0) ? v1.x : (j == 1) ? v1.y : (j == 2) ? v1.z : v1.w;
            float4 w = lw4[(fb * 4 + j) * 40 + g];
            a0.x = fmaf(s0, w.x, a0.x); a0.y = fmaf(s0, w.y, a0.y);
            a0.z = fmaf(s0, w.z, a0.z); a0.w = fmaf(s0, w.w, a0.w);
            a1.x = fmaf(s1, w.x, a1.x); a1.y = fmaf(s1, w.y, a1.y);
            a1.z = fmaf(s1, w.z, a1.z); a1.w = fmaf(s1, w.w, a1.w);
        }
    }
    if (g < 32) {
        uint2 u0, u1;
        u0.x = f2bf(a0.x) | ((unsigned)f2bf(a0.y) << 16);
        u0.y = f2bf(a0.z) | ((unsigned)f2bf(a0.w) << 16);
        u1.x = f2bf(a1.x) | ((unsigned)f2bf(a1.y) << 16);
        u1.y = f2bf(a1.z) | ((unsigned)f2bf(a1.w) << 16);
        *(uint2*)(outk + (size_t)n0 * (KS * HID) + g * 4) = u0;
        *(uint2*)(outk + (size_t)(n0 + 1) * (KS * HID) + g * 4) = u1;
    } else {
        int o = 4 * g - 128;
        *(float4*)(outr + (size_t)n0 * HID + o) = a0;
        *(float4*)(outr + (size_t)(n0 + 1) * HID + o) = a1;
    }
}

__global__ void xw2_kernel(const float* __restrict__ H, const float* __restrict__ W,
                           const float* __restrict__ R, unsigned short* __restrict__ outk,
                           float* __restrict__ outr, int n) {
    __shared__ float lw2[32 * 50];
    int t = threadIdx.x;
    for (int i = t; i < 32 * 50; i += 256) {
        int f = i / 50;
        int col = i - f * 50;
        lw2[i] = (col < 40) ? W[(size_t)(col / 10) * (32 * 10) + f * 10 + (col % 10)]
                            : R[f * 10 + (col - 40)];
    }
    __syncthreads();
    int total = (n / 2) * 25;
    int id = blockIdx.x * blockDim.x + t;
    if (id >= total) return;
    int p = id % 25;
    int pr = id / 25;
    int n0 = 2 * pr;
    const float4* H0 = (const float4*)(H + (size_t)n0 * HID);
    const float4* H1 = (const float4*)(H + (size_t)(n0 + 1) * HID);
    float4 h0[8], h1[8];
#pragma unroll
    for (int i = 0; i < 8; ++i) { h0[i] = H0[i]; h1[i] = H1[i]; }
    const float2* lwp = (const float2*)lw2;  // lwp[f*25 + p]
    float ax0 = 0.f, ay0 = 0.f, ax1 = 0.f, ay1 = 0.f;
#pragma unroll
    for (int fb = 0; fb < 8; ++fb) {
        float4 v0 = h0[fb], v1 = h1[fb];
#pragma unroll
        for (int j = 0; j < 4; ++j) {
            float s0 = (j == 0) ? v0.x : (j == 1) ? v0.y : (j == 2) ? v0.z : v0.w;
            float s1 = (j == 0) ? v1.x : (j == 1) ? v1.y : (j == 2) ? v1.z : v1.w;
            float2 w = lwp[(fb * 4 + j) * 25 + p];
            ax0 = fmaf(s0, w.x, ax0); ay0 = fmaf(s0, w.y, ay0);
            ax1 = fmaf(s1, w.x, ax1); ay1 = fmaf(s1, w.y, ay1);
        }
    }
    int col = 2 * p;
    if (col < KS * NCLS) {
        *(unsigned*)(outk + (size_t)n0 * (KS * NCLS) + col) =
            f2bf(ax0) | ((unsigned)f2bf(ay0) << 16);
        *(unsigned*)(outk + (size_t)(n0 + 1) * (KS * NCLS) + col) =
            f2bf(ax1) | ((unsigned)f2bf(ay1) << 16);
    } else {
        int o = col - KS * NCLS;
        *(float2*)(outr + (size_t)n0 * NCLS + o) = make_float2(ax0, ay0);
        *(float2*)(outr + (size_t)(n0 + 1) * NCLS + o) = make_float2(ax1, ay1);
    }
}

// ---------- aggregation (wave-per-node, 4 edges in flight) ----------

__device__ inline float interp32(const unsigned short* __restrict__ xwk, unsigned p, int c) {
    int src = p & 0xFFFF;
    int k0 = (p >> 16) & 3;
    int k1 = min(k0 + 1, KS - 1);
    float fr = (float)(p >> 18) * (1.f / 16383.f);
    const unsigned short* row = xwk + (size_t)src * (KS * HID);
    float v0 = bf2f(row[k0 * HID + c]);
    float v1 = bf2f(row[k1 * HID + c]);
    return fmaf(fr, v1 - v0, v0);
}

// One 64-lane wave per node: lane = (half, channel). Each half strides its
// own parity stream (stride 2), unrolled 2x -> 4 edges / 8 loads in flight.
__global__ void agg1_kernel(const unsigned short* __restrict__ xwk,
                            const float* __restrict__ xroot,
                            const int* __restrict__ offs, const unsigned* __restrict__ spk,
                            const float* __restrict__ bias, float* __restrict__ h, int n) {
    int lane = threadIdx.x & 63;
    int c = lane & 31;
    int half = lane >> 5;
    int node = blockIdx.x * 4 + (threadIdx.x >> 6);
    if (node >= n) return;
    int beg = offs[node];
    int end = offs[node + 1];
    float s0 = 0.f, s1 = 0.f;
    int e = beg + half;
    while (e + 2 < end) {
        unsigned p0 = spk[e];
        unsigned p1 = spk[e + 2];
        s0 += interp32(xwk, p0, c);
        s1 += interp32(xwk, p1, c);
        e += 4;
    }
    if (e < end) s0 += interp32(xwk, spk[e], c);
    float sum = s0 + s1;
    sum += __shfl_xor(sum, 32, 64);  // merge halves
    int deg = end - beg;
    float m = sum / (float)(deg > 0 ? deg : 1);
    float o = m + xroot[(size_t)node * HID + c] + bias[c];
    if (half == 0) h[(size_t)node * HID + c] = (o > 0.f) ? o : expm1f(o);
}

__device__ inline float interp10(const unsigned short* __restrict__ xwk, unsigned p, int cc) {
    int src = p & 0xFFFF;
    int k0 = (p >> 16) & 3;
    int k1 = min(k0 + 1, KS - 1);
    float fr = (float)(p >> 18) * (1.f / 16383.f);
    const unsigned short* row = xwk + (size_t)src * (KS * NCLS);
    float v0 = bf2f(row[k0 * NCLS + cc]);
    float v1 = bf2f(row[k1 * NCLS + cc]);
    return fmaf(fr, v1 - v0, v0);
}

// 32 lanes per node: lane = (parity, channel16). Parity streams unrolled 2x.
__global__ void agg2_kernel(const unsigned short* __restrict__ xwk,
                            const float* __restrict__ xroot,
                            const int* __restrict__ offs, const unsigned* __restrict__ spk,
                            const float* __restrict__ bias, float* __restrict__ out, int n) {
    int g = threadIdx.x & 31;
    int c = g & 15;
    int par = g >> 4;
    int node = blockIdx.x * 8 + (threadIdx.x >> 5);
    if (node >= n) return;
    int cc = min(c, NCLS - 1);
    int beg = offs[node];
    int end = offs[node + 1];
    float s0 = 0.f, s1 = 0.f;
    int e = beg + par;
    while (e + 2 < end) {
        unsigned p0 = spk[e];
        unsigned p1 = spk[e + 2];
        s0 += interp10(xwk, p0, cc);
        s1 += interp10(xwk, p1, cc);
        e += 4;
    }
    if (e < end) s0 += interp10(xwk, spk[e], cc);
    float sum = s0 + s1;
    sum += __shfl_xor(sum, 16, 32);  // merge parities
    int deg = end - beg;
    float m = sum / (float)(deg > 0 ? deg : 1);
    float logit = m + xroot[(size_t)node * NCLS + cc] + bias[cc];
    bool active = (c < NCLS);
    float mx = active ? logit : -INFINITY;
#pragma unroll
    for (int msk = 1; msk < 16; msk <<= 1) mx = fmaxf(mx, __shfl_xor(mx, msk, 16));
    float ex = active ? expf(logit - mx) : 0.f;
    float s = ex;
#pragma unroll
    for (int msk = 1; msk < 16; msk <<= 1) s += __shfl_xor(s, msk, 16);
    if (active && par == 0) out[(size_t)node * NCLS + c] = (logit - mx) - logf(s);
}

extern "C" void kernel_launch(void* const* d_in, const int* in_sizes, int n_in,
                              void* d_out, int out_size, void* d_ws, size_t ws_size,
                              hipStream_t stream) {
    const float* x       = (const float*)d_in[0];
    const int*   ei      = (const int*)d_in[1];
    const float* ea      = (const float*)d_in[2];
    const float* W1      = (const float*)d_in[3];
    const float* root1   = (const float*)d_in[4];
    const float* bias1   = (const float*)d_in[5];
    const float* W2      = (const float*)d_in[6];
    const float* root2   = (const float*)d_in[7];
    const float* bias2   = (const float*)d_in[8];
    float* out = (float*)d_out;

    const int N = in_sizes[0] / F_IN;      // 50000
    const int E = in_sizes[2];             // 1600000
    const int NB = (N + 255) >> BKT_SH;    // 196

    char* base = (char*)d_ws;
    size_t off = 0;
    auto alloc = [&](size_t bytes) {
        char* p = base + off;
        off = (off + bytes + 255) & ~(size_t)255;
        return (void*)p;
    };
    unsigned short* xwk1 = (unsigned short*)alloc((size_t)N * KS * HID * 2); // 12.8 MB
    float* xr1           = (float*)alloc((size_t)N * HID * 4);               // 6.4 MB
    float* h             = (float*)alloc((size_t)N * HID * 4);               // 6.4 MB
    int* offs            = (int*)alloc(((size_t)N + 1) * 4);
    int* bcnt            = (int*)alloc((size_t)NB * 4);
    int* bbase           = (int*)alloc(((size_t)NB + 1) * 4);
    int* gcur            = (int*)alloc((size_t)NB * 4);
    unsigned* spk        = (unsigned*)alloc((size_t)E * 4);                  // 6.4 MB
    uint2* tpd           = (uint2*)xwk1;  // aliases xwk1 (dead before xw1)
    unsigned short* xwk2 = xwk1;
    float* xr2           = xr1;
    if (ws_size < off) return;

    int ebk = (E + TILE - 1) / TILE;

    hipMemsetAsync(bcnt, 0, (size_t)NB * 4, stream);
    bucket_hist_kernel<<<ebk, 256, 0, stream>>>(ei, bcnt, E, NB);
    mini_scan_kernel<<<1, 256, 0, stream>>>(bcnt, bbase, gcur, NB);
    bucket_scatter_kernel<<<ebk, 256, 0, stream>>>(ei, ea, gcur, tpd, E, NB);
    node_sort_kernel<<<NB, 256, 0, stream>>>(tpd, bbase, spk, offs, N, NB);
    // xw1 after node_sort (tpd aliases xwk1)
    xw1_kernel<<<(N + 15) / 16, 320, 0, stream>>>(x, W1, root1, xwk1, xr1, N);
    agg1_kernel<<<(N + 3) / 4, 256, 0, stream>>>(xwk1, xr1, offs, spk, bias1, h, N);
    {
        int total = (N / 2) * 25;
        xw2_kernel<<<(total + 255) / 256, 256, 0, stream>>>(h, W2, root2, xwk2, xr2, N);
    }
    agg2_kernel<<<(N + 7) / 8, 256, 0, stream>>>(xwk2, xr2, offs, spk, bias2, out, N);
}